// Round 1
// baseline (2762.204 us; speedup 1.0000x reference)
//
#include <hip/hip_runtime.h>

#define DD 512
#define BB 64
#define VV 32000
#define TT 32

typedef __attribute__((ext_vector_type(8))) short short8;
typedef __attribute__((ext_vector_type(4))) float f32x4;
typedef __attribute__((ext_vector_type(4))) unsigned short ushort4v;

__device__ __forceinline__ float sigm(float x) { return 1.0f / (1.0f + __expf(-x)); }
__device__ __forceinline__ float ftanh(float x) {
  float e = __expf(2.0f * x);
  return 1.0f - 2.0f / (e + 1.0f);
}
__device__ __forceinline__ unsigned short f2bf(float f) {
  unsigned int u = __float_as_uint(f);
  u = (u + 0x7FFFu + ((u >> 16) & 1u)) >> 16;
  return (unsigned short)u;
}

// ---- one-time prep: vocab fp32 -> bf16 bits ----
__global__ __launch_bounds__(256) void prep_vocab_k(const float* __restrict__ v,
                                                    unsigned short* __restrict__ o) {
  size_t i = (size_t)blockIdx.x * 256 + threadIdx.x;  // 4,096,000 float4s exactly
  float4 x = ((const float4*)v)[i];
  ushort4v y;
  y.x = f2bf(x.x); y.y = f2bf(x.y); y.z = f2bf(x.z); y.w = f2bf(x.w);
  ((ushort4v*)o)[i] = y;
}

// ---- one-time init: h=c=feats, emb = vocab_emb[0] broadcast ----
__global__ __launch_bounds__(256) void init_k(const float* __restrict__ feats,
                                              const float* __restrict__ vocab,
                                              float* __restrict__ h, float* __restrict__ c,
                                              float* __restrict__ emb) {
  int i = blockIdx.x * 256 + threadIdx.x;  // 32768 total
  float f = feats[i];
  h[i] = f; c[i] = f;
  emb[i] = vocab[i & 511];
}

// ---- LSTM cell: gates = emb@Wih.T + bih + h@Whh.T + bhh; update h,c ----
// grid 256 = (4 bgroups of 16 b) x (64 colgroups of 8 d), block 256
__global__ __launch_bounds__(256) void cell_k(const float* __restrict__ Wih, const float* __restrict__ Whh,
    const float* __restrict__ bih, const float* __restrict__ bhh,
    const float* __restrict__ emb, const float* __restrict__ h_old, const float* __restrict__ c_old,
    float* __restrict__ h_new, float* __restrict__ c_new)
{
  __shared__ float4 xs4[16][128];
  __shared__ float4 hs4[16][128];
  __shared__ float gv[8][4][16];
  int tid = threadIdx.x;
  int bg = blockIdx.x >> 6, cg = blockIdx.x & 63;
  int b0 = bg * 16, d0 = cg * 8;
  const float4* ep = (const float4*)emb;
  const float4* hp = (const float4*)h_old;
  for (int i = tid; i < 2048; i += 256) {
    int b = i >> 7, k4 = i & 127;
    xs4[b][k4] = ep[(size_t)(b0 + b) * 128 + k4];
    hs4[b][k4] = hp[(size_t)(b0 + b) * 128 + k4];
  }
  __syncthreads();
  int rl = tid & 31, dl = rl >> 2, gate = rl & 3, bl = tid >> 5;
  int r = gate * 512 + d0 + dl;  // W row (gate order i,f,g,o)
  const float4* wi = (const float4*)(Wih + (size_t)r * 512);
  const float4* wh = (const float4*)(Whh + (size_t)r * 512);
  float acc0 = 0.f, acc1 = 0.f;
#pragma unroll 4
  for (int k4 = 0; k4 < 128; k4++) {
    float4 a = wi[k4], w = wh[k4];
    float4 x0 = xs4[bl][k4], x1 = xs4[bl + 8][k4];
    float4 h0 = hs4[bl][k4], h1 = hs4[bl + 8][k4];
    acc0 = fmaf(a.x, x0.x, acc0); acc0 = fmaf(a.y, x0.y, acc0);
    acc0 = fmaf(a.z, x0.z, acc0); acc0 = fmaf(a.w, x0.w, acc0);
    acc0 = fmaf(w.x, h0.x, acc0); acc0 = fmaf(w.y, h0.y, acc0);
    acc0 = fmaf(w.z, h0.z, acc0); acc0 = fmaf(w.w, h0.w, acc0);
    acc1 = fmaf(a.x, x1.x, acc1); acc1 = fmaf(a.y, x1.y, acc1);
    acc1 = fmaf(a.z, x1.z, acc1); acc1 = fmaf(a.w, x1.w, acc1);
    acc1 = fmaf(w.x, h1.x, acc1); acc1 = fmaf(w.y, h1.y, acc1);
    acc1 = fmaf(w.z, h1.z, acc1); acc1 = fmaf(w.w, h1.w, acc1);
  }
  float bias = bih[r] + bhh[r];
  gv[dl][gate][bl] = acc0 + bias;
  gv[dl][gate][bl + 8] = acc1 + bias;
  __syncthreads();
  if (tid < 128) {
    int b = tid & 15, dx = tid >> 4;
    float gi = gv[dx][0][b], gf = gv[dx][1][b], gg = gv[dx][2][b], go = gv[dx][3][b];
    size_t idx = (size_t)(b0 + b) * 512 + d0 + dx;
    float c2 = sigm(gf) * c_old[idx] + sigm(gi) * ftanh(gg);
    c_new[idx] = c2;
    h_new[idx] = sigm(go) * ftanh(c2);
  }
}

// ---- attention pass 1: Zpart[iq][b][j] = sum_{i in chunk} exp(f_i * h_j) ----
// grid 256 = b*4 + iq, block 512 (thread = j)
__global__ __launch_bounds__(512) void attnZ_k(const float* __restrict__ feats,
    const float* __restrict__ h, float* __restrict__ Zpart)
{
  int b = blockIdx.x >> 2, iq = blockIdx.x & 3;
  int tid = threadIdx.x;
  __shared__ float fs[128];
  if (tid < 128) fs[tid] = feats[b * 512 + iq * 128 + tid];
  __syncthreads();
  float hj = h[b * 512 + tid];
  float p = 0.f;
#pragma unroll 8
  for (int ii = 0; ii < 128; ii++) p += __expf(fs[ii] * hj);
  Zpart[(size_t)(iq * 64 + b) * 512 + tid] = p;
}

// ---- attention pass 2: ctxpart[jq][b][i] = sum_{j in chunk} exp(f_i*h_j)*f_j/Z_j ----
// grid 256 = b*4 + jq, block 512 (thread = i)
__global__ __launch_bounds__(512) void attnC_k(const float* __restrict__ feats,
    const float* __restrict__ h, const float* __restrict__ Zpart, float* __restrict__ ctxp)
{
  int b = blockIdx.x >> 2, jq = blockIdx.x & 3;
  int tid = threadIdx.x;
  __shared__ float hw[128], ww[128];
  if (tid < 128) {
    int j = jq * 128 + tid;
    float Z = Zpart[(size_t)(0 * 64 + b) * 512 + j] + Zpart[(size_t)(1 * 64 + b) * 512 + j]
            + Zpart[(size_t)(2 * 64 + b) * 512 + j] + Zpart[(size_t)(3 * 64 + b) * 512 + j];
    hw[tid] = h[b * 512 + j];
    ww[tid] = feats[b * 512 + j] / Z;
  }
  __syncthreads();
  float fi = feats[b * 512 + tid];
  float p = 0.f;
#pragma unroll 8
  for (int jj = 0; jj < 128; jj++) p += __expf(fi * hw[jj]) * ww[jj];
  ctxp[(size_t)(jq * 64 + b) * 512 + tid] = p;
}

// ---- z = [h|ctx] @ Whc.T + bhc ----
// grid 256 = (4 bgroups of 16) x (64 colgroups of 8), block 256
__global__ __launch_bounds__(256) void zgemm_k(const float* __restrict__ h,
    const float* __restrict__ ctxp, const float* __restrict__ Whc, const float* __restrict__ bhc,
    float* __restrict__ z)
{
  __shared__ float4 hs4[16][128];
  __shared__ float4 cs4[16][128];
  __shared__ float zp[2][16][8];
  int tid = threadIdx.x;
  int bg = blockIdx.x >> 6, cg = blockIdx.x & 63;
  int b0 = bg * 16, d0 = cg * 8;
  const float4* hp = (const float4*)h;
  const float4* cp = (const float4*)ctxp;
  for (int i = tid; i < 2048; i += 256) {
    int b = i >> 7, k4 = i & 127;
    hs4[b][k4] = hp[(size_t)(b0 + b) * 128 + k4];
    float4 s0 = cp[(size_t)(0 * 64 + b0 + b) * 128 + k4];
    float4 s1 = cp[(size_t)(1 * 64 + b0 + b) * 128 + k4];
    float4 s2 = cp[(size_t)(2 * 64 + b0 + b) * 128 + k4];
    float4 s3 = cp[(size_t)(3 * 64 + b0 + b) * 128 + k4];
    float4 s; s.x = s0.x+s1.x+s2.x+s3.x; s.y = s0.y+s1.y+s2.y+s3.y;
    s.z = s0.z+s1.z+s2.z+s3.z; s.w = s0.w+s1.w+s2.w+s3.w;
    cs4[b][k4] = s;
  }
  __syncthreads();
  int dl = tid & 7, b = (tid >> 3) & 15, kh = tid >> 7;
  int dcol = d0 + dl;
  const float4* wr = (const float4*)(Whc + (size_t)dcol * 1024 + (size_t)kh * 512);
  float4 (*src)[128] = kh ? cs4 : hs4;
  float acc = 0.f;
#pragma unroll 4
  for (int k4 = 0; k4 < 128; k4++) {
    float4 w = wr[k4], x = src[b][k4];
    acc = fmaf(w.x, x.x, acc); acc = fmaf(w.y, x.y, acc);
    acc = fmaf(w.z, x.z, acc); acc = fmaf(w.w, x.w, acc);
  }
  zp[kh][b][dl] = acc;
  __syncthreads();
  if (tid < 128) {
    int bb = tid >> 3, dd = tid & 7;
    z[(size_t)(b0 + bb) * 512 + d0 + dd] = zp[0][bb][dd] + zp[1][bb][dd] + bhc[d0 + dd];
  }
}

// ---- LayerNorm + tanh -> emb (fp32 + bf16) ----
// grid 64 (b), block 256
__global__ __launch_bounds__(256) void ln_k(const float* __restrict__ z, const float* __restrict__ gamma,
    const float* __restrict__ beta, float* __restrict__ emb, unsigned short* __restrict__ emb_bf)
{
  int b = blockIdx.x, tid = threadIdx.x;
  __shared__ float zs[512];
  __shared__ float rs[256], rq[256];
  float a = z[b * 512 + tid], d = z[b * 512 + 256 + tid];
  zs[tid] = a; zs[tid + 256] = d;
  rs[tid] = a + d; rq[tid] = a * a + d * d;
  __syncthreads();
  for (int s = 128; s > 0; s >>= 1) {
    if (tid < s) { rs[tid] += rs[tid + s]; rq[tid] += rq[tid + s]; }
    __syncthreads();
  }
  float mean = rs[0] * (1.0f / 512.0f);
  float var = rq[0] * (1.0f / 512.0f) - mean * mean;
  float rstd = rsqrtf(var + 1e-5f);
  for (int d2 = tid; d2 < 512; d2 += 256) {
    float xn = (zs[d2] - mean) * rstd;
    float e = ftanh(xn * gamma[d2] + beta[d2]);
    emb[b * 512 + d2] = e;
    emb_bf[b * 512 + d2] = f2bf(e);
  }
}

// ---- logits = emb @ vocab.T + bias, bf16 MFMA 16x16x32 ----
// grid 500 (N tiles of 64), block 256 (4 waves; wave w does M-rows [16w,16w+16) x all 64 N)
__global__ __launch_bounds__(256) void logits_k(const unsigned short* __restrict__ emb_bf,
    const unsigned short* __restrict__ vocab_bf, const float* __restrict__ vbias,
    float* __restrict__ out)
{
  int n0 = blockIdx.x * 64;
  int w = threadIdx.x >> 6, l = threadIdx.x & 63;
  int lm = l & 15, kb = l >> 4;
  int m = w * 16 + lm;
  f32x4 acc[4] = {};
  const short8* ap = (const short8*)(emb_bf + (size_t)m * 512);
  for (int kt = 0; kt < 16; kt++) {
    short8 a = ap[kt * 4 + kb];
#pragma unroll
    for (int nt = 0; nt < 4; nt++) {
      const short8* bp = (const short8*)(vocab_bf + (size_t)(n0 + nt * 16 + lm) * 512);
      short8 bv = bp[kt * 4 + kb];
      acc[nt] = __builtin_amdgcn_mfma_f32_16x16x32_bf16(a, bv, acc[nt], 0, 0, 0);
    }
  }
  int rbase = w * 16 + kb * 4;  // D layout: col = lane&15, row = (lane>>4)*4 + reg
#pragma unroll
  for (int nt = 0; nt < 4; nt++) {
    int v = n0 + nt * 16 + lm;
    float bias = vbias[v];
#pragma unroll
    for (int r = 0; r < 4; r++) {
      out[(size_t)(rbase + r) * 32000 + v] = acc[nt][r] + bias;
    }
  }
}

extern "C" void kernel_launch(void* const* d_in, const int* in_sizes, int n_in,
                              void* d_out, int out_size, void* d_ws, size_t ws_size,
                              hipStream_t stream) {
  const float* feats = (const float*)d_in[0];
  const float* Wih  = (const float*)d_in[1];
  const float* Whh  = (const float*)d_in[2];
  const float* bih  = (const float*)d_in[3];
  const float* bhh  = (const float*)d_in[4];
  const float* Whc  = (const float*)d_in[5];
  const float* bhc  = (const float*)d_in[6];
  const float* gam  = (const float*)d_in[7];
  const float* bet  = (const float*)d_in[8];
  const float* vemb = (const float*)d_in[9];
  const float* vbias= (const float*)d_in[10];
  float* out = (float*)d_out;

  char* p = (char*)d_ws;
  unsigned short* vocab_bf = (unsigned short*)p; p += (size_t)VV * DD * 2;   // 32.77 MB
  float* hA  = (float*)p; p += BB * DD * 4;
  float* hB  = (float*)p; p += BB * DD * 4;
  float* cA  = (float*)p; p += BB * DD * 4;
  float* cB  = (float*)p; p += BB * DD * 4;
  float* emb = (float*)p; p += BB * DD * 4;
  float* zb  = (float*)p; p += BB * DD * 4;
  unsigned short* emb_bf = (unsigned short*)p; p += BB * DD * 2;
  float* Zpart = (float*)p; p += (size_t)4 * BB * DD * 4;
  float* ctxp  = (float*)p; p += (size_t)4 * BB * DD * 4;

  prep_vocab_k<<<16000, 256, 0, stream>>>(vemb, vocab_bf);
  init_k<<<128, 256, 0, stream>>>(feats, vemb, hA, cA, emb);

  for (int t = 0; t < TT; t++) {
    float* ho = (t & 1) ? hB : hA; float* hn = (t & 1) ? hA : hB;
    float* co = (t & 1) ? cB : cA; float* cn = (t & 1) ? cA : cB;
    cell_k<<<256, 256, 0, stream>>>(Wih, Whh, bih, bhh, emb, ho, co, hn, cn);
    attnZ_k<<<256, 512, 0, stream>>>(feats, hn, Zpart);
    attnC_k<<<256, 512, 0, stream>>>(feats, hn, Zpart, ctxp);
    zgemm_k<<<256, 256, 0, stream>>>(hn, ctxp, Whc, bhc, zb);
    ln_k<<<64, 256, 0, stream>>>(zb, gam, bet, emb, emb_bf);
    logits_k<<<500, 256, 0, stream>>>(emb_bf, vocab_bf, vbias, out + (size_t)t * BB * VV);
  }
}